// Round 3
// baseline (3322.897 us; speedup 1.0000x reference)
//
#include <hip/hip_runtime.h>
#include <math.h>

#define B_    64
#define L_    32
#define D_    64
#define NV_   100000
#define TIN_  8
#define THID_ 128
#define LROWS_ 1856   // 64*29 loss rows
#define EROWS_ 192    // 64*3 eval rows
#define NTILES_ 3125  // 100000/32 exact
#define CHUNK_  125   // tiles per chunk
#define NCHUNK_ 25    // chunks; 25*125 = 3125 exact
#define LOG2E_ 1.44269504088896f

// workspace layout (float-element offsets into ws)
#define WS_TIME_EMB 0        // 2048*64 f32
#define WS_XIH      131072   // 2048*64 f32
#define WS_SEQ      262144   // 2048*64 f32 (unscaled, for lt/fin)
#define WS_LT       393216   // 2048 f32
#define WS_T1       395264   // 1856 f32 (zeroed by embed_xih)
#define WS_RANK     397120   // 192 int  (zeroed by embed_xih; contiguous after T1)
#define WS_SEQH     397312   // 2048*64 ushort (bf16 hi of seq*log2e)
#define WS_SEQL     462848   // 2048*64 ushort (bf16 lo of seq*log2e)
#define WS_VTH      528384   // 100000*64 ushort (bf16 hi of vt)
#define WS_VTL      3728384  // 100000*64 ushort (bf16 lo of vt)
// end: 6928384 floats = 27.7 MB

typedef __attribute__((ext_vector_type(8)))  short s8b;   // 8 bf16 = 4 VGPR
typedef __attribute__((ext_vector_type(16))) float f16f;  // MFMA 32x32 acc

__device__ __forceinline__ unsigned short f2bf(float x) {  // RNE fp32->bf16
    unsigned u = __float_as_uint(x);
    unsigned r = u + 0x7fffu + ((u >> 16) & 1u);
    return (unsigned short)(r >> 16);
}
__device__ __forceinline__ float bf2f(unsigned short h) {
    return __uint_as_float(((unsigned)h) << 16);
}

// ---------------- kernel 0: venue_table fp32 -> bf16 hi/lo split -------------
__global__ __launch_bounds__(256)
void vtcvt_kernel(const float* __restrict__ vt, float* __restrict__ ws)
{
    unsigned short* vh = (unsigned short*)(ws + WS_VTH);
    unsigned short* vl = (unsigned short*)(ws + WS_VTL);
    const int idx = blockIdx.x * 256 + threadIdx.x;   // 0..1599999 (float4 units)
    const float4 x = ((const float4*)vt)[idx];
    ushort4 h, l;
    h.x = f2bf(x.x); l.x = f2bf(x.x - bf2f(h.x));
    h.y = f2bf(x.y); l.y = f2bf(x.y - bf2f(h.y));
    h.z = f2bf(x.z); l.z = f2bf(x.z - bf2f(h.z));
    h.w = f2bf(x.w); l.w = f2bf(x.w - bf2f(h.w));
    *(ushort4*)(vh + idx * 4) = h;
    *(ushort4*)(vl + idx * 4) = l;
}

// ---------------- kernel 1: fused time-MLP + gather + xih + accum zeroing ----
// 512 blocks x 256 threads; one row per wave.
__global__ __launch_bounds__(256)
void embed_xih_kernel(const int* __restrict__ venue, const float* __restrict__ timef,
                      const float* __restrict__ vt, const float* __restrict__ w1,
                      const float* __restrict__ b1, const float* __restrict__ w2,
                      const float* __restrict__ b2, const float* __restrict__ Wih,
                      const float* __restrict__ bih, const float* __restrict__ bhh,
                      float* __restrict__ ws)
{
    float* time_emb = ws + WS_TIME_EMB;
    float* xih = ws + WS_XIH;
    const int wave = threadIdx.x >> 6, d = threadIdx.x & 63;
    const int row = blockIdx.x * 4 + wave;          // 0..2047
    const int g = blockIdx.x * 256 + threadIdx.x;
    if (g < LROWS_ + EROWS_) ws[WS_T1 + g] = 0.f;   // zero T1 (1856) + rank (192)
    __shared__ float hid[4][THID_];
    __shared__ float xrow[4][D_];
    float t[TIN_];
#pragma unroll
    for (int k = 0; k < TIN_; ++k) t[k] = timef[row*TIN_ + k];
#pragma unroll
    for (int h = d; h < THID_; h += 64) {
        float s = b1[h];
#pragma unroll
        for (int k = 0; k < TIN_; ++k) s = fmaf(t[k], w1[k*THID_ + h], s);
        hid[wave][h] = fmaxf(s, 0.f);
    }
    __syncthreads();
    float v = b2[d];
#pragma unroll 16
    for (int h = 0; h < THID_; ++h) v = fmaf(hid[wave][h], w2[h*D_ + d], v);
    time_emb[row*D_ + d] = v;
    xrow[wave][d] = vt[(size_t)venue[row]*D_ + d] + v;
    __syncthreads();
    float acc = bih[d] + bhh[d];
    const float* wr = Wih + (size_t)d*D_;
#pragma unroll 16
    for (int k = 0; k < D_; ++k) acc = fmaf(xrow[wave][k], wr[k], acc);
    xih[row*D_ + d] = acc;
}

// ---------------- kernel 2: RNN, one wave per batch element ------------------
__device__ __forceinline__ void store_seq(float* __restrict__ ws, int gr, int d, float v)
{
    (ws + WS_SEQ)[gr*D_ + d] = v;                 // unscaled fp32 for lt
    const float sv = v * LOG2E_;                  // scaled: exp(l) = exp2(acc)
    const unsigned short hb = f2bf(sv);
    const unsigned short lb = f2bf(sv - bf2f(hb));
    ((unsigned short*)(ws + WS_SEQH))[gr*D_ + d] = hb;
    ((unsigned short*)(ws + WS_SEQL))[gr*D_ + d] = lb;
}

__global__ __launch_bounds__(64)
void rnn_kernel(const int* __restrict__ user, const float* __restrict__ user_table,
                const float* __restrict__ Whh, float* __restrict__ ws)
{
    const float* time_emb = ws + WS_TIME_EMB;
    const float* xih = ws + WS_XIH;
    const int b = blockIdx.x, d = threadIdx.x;
    __shared__ float h_lds[D_];
    float whh[D_];
#pragma unroll
    for (int k = 0; k < D_; ++k) whh[k] = Whh[d*D_ + k];
    float h = user_table[(size_t)user[b]*D_ + d];
    for (int l = 0; l < 31; ++l) {
        const float te = time_emb[(b*L_ + l)*D_ + d];
        const int gr = (l < 29) ? (b*29 + l) : (LROWS_ + b*3 + (l - 29));
        store_seq(ws, gr, d, h - te);
        h_lds[d] = h;
        __syncthreads();
        float acc = xih[(b*L_ + l)*D_ + d];
#pragma unroll
        for (int k = 0; k < D_; ++k) acc = fmaf(whh[k], h_lds[k], acc);
        __syncthreads();
        h = tanhf(acc);
    }
    store_seq(ws, LROWS_ + b*3 + 2, d, h - time_emb[(b*L_ + 31)*D_ + d]);
}

// ---------------- kernel 3: target logits l_t for all 2048 rows (fp32) -------
__global__ __launch_bounds__(256)
void lt_kernel(const int* __restrict__ venue, const float* __restrict__ vt,
               float* __restrict__ ws)
{
    const float* seq = ws + WS_SEQ;
    float* lt = ws + WS_LT;
    const int wid = threadIdx.x >> 6, lane = threadIdx.x & 63;
    const int row = blockIdx.x*4 + wid;      // 0..2047
    int tgt;
    if (row < LROWS_) {
        const int b = row/29, l = row - b*29;
        tgt = venue[b*L_ + l];
    } else {
        const int r2 = row - LROWS_;
        const int b = r2/3, j = r2 - b*3;
        tgt = venue[b*L_ + 29 + j];
    }
    float v = seq[(size_t)row*D_ + lane] * vt[(size_t)tgt*D_ + lane];
#pragma unroll
    for (int m = 32; m >= 1; m >>= 1) v += __shfl_xor(v, m, 64);
    if (lane == 0) lt[row] = v;
}

// ---------------- kernel 4: fused MFMA GEMM (loss: bf16 + exp2-sum; eval:
// bf16x3 + rank count). grid (35, 25): x<29 loss 64-row blocks, x>=29 eval
// 32-row blocks; y = venue chunk of 125 tiles, 4 waves stride the tiles.
__global__ __launch_bounds__(256)
void gemm_kernel(const int* __restrict__ venue, float* __restrict__ ws)
{
    const unsigned short* seq_hi = (const unsigned short*)(ws + WS_SEQH);
    const unsigned short* seq_lo = (const unsigned short*)(ws + WS_SEQL);
    const unsigned short* vt_hi  = (const unsigned short*)(ws + WS_VTH);
    const unsigned short* vt_lo  = (const unsigned short*)(ws + WS_VTL);
    const int lane = threadIdx.x & 63, wave = threadIdx.x >> 6;
    const int col = lane & 31, half = lane >> 5;
    const int tile0 = blockIdx.y * CHUNK_;
    const int laneoff = col*64 + half*8;      // within-tile short offset

    if (blockIdx.x < 29) {
        // ---------- loss: 64 rows, hi-only (pure bf16), depth-2 prefetch ring
        float* t1acc = ws + WS_T1;
        const int rowbase = blockIdx.x * 64;
        s8b Ah[2][4];
#pragma unroll
        for (int t = 0; t < 2; ++t)
#pragma unroll
            for (int s = 0; s < 4; ++s)
                Ah[t][s] = *(const s8b*)(seq_hi + (rowbase + t*32 + col)*64 + s*16 + half*8);
        float t1a[16], t1b[16];
#pragma unroll
        for (int i = 0; i < 16; ++i) { t1a[i] = 0.f; t1b[i] = 0.f; }
        s8b Bb[2][4];
        {
            const unsigned short* p0 = vt_hi + (size_t)(tile0 + wave)*2048 + laneoff;
            const unsigned short* p1 = vt_hi + (size_t)(tile0 + wave + 4)*2048 + laneoff;
#pragma unroll
            for (int s = 0; s < 4; ++s) {
                Bb[0][s] = *(const s8b*)(p0 + s*16);
                Bb[1][s] = *(const s8b*)(p1 + s*16);
            }
        }
        for (int it = wave; it < CHUNK_; it += 4) {
            const int p = ((it - wave) >> 2) & 1;
            int pf = tile0 + it + 8; if (pf >= NTILES_) pf -= NTILES_;   // wrap: always valid
            const unsigned short* pp = vt_hi + (size_t)pf*2048 + laneoff;
            f16f acc0 = {}, acc1 = {};
#pragma unroll
            for (int s = 0; s < 4; ++s) {
                acc0 = __builtin_amdgcn_mfma_f32_32x32x16_bf16(Ah[0][s], Bb[p][s], acc0, 0, 0, 0);
                acc1 = __builtin_amdgcn_mfma_f32_32x32x16_bf16(Ah[1][s], Bb[p][s], acc1, 0, 0, 0);
                Bb[p][s] = *(const s8b*)(pp + s*16);   // consumed 2 iterations later
            }
#pragma unroll
            for (int i = 0; i < 16; ++i) {
                t1a[i] += __builtin_amdgcn_exp2f(acc0[i]);
                t1b[i] += __builtin_amdgcn_exp2f(acc1[i]);
            }
        }
        // reduce over the 32 venue-cols in each half, one atomic per row
#pragma unroll
        for (int i = 0; i < 16; ++i) {
            float a = t1a[i], b = t1b[i];
#pragma unroll
            for (int m = 1; m <= 16; m <<= 1) {
                a += __shfl_xor(a, m, 64);
                b += __shfl_xor(b, m, 64);
            }
            t1a[i] = a; t1b[i] = b;
        }
        if (col == 0) {
#pragma unroll
            for (int i = 0; i < 16; ++i) {
                const int r = (i & 3) + 8*(i >> 2) + 4*half;
                atomicAdd(&t1acc[rowbase + r], t1a[i]);
                atomicAdd(&t1acc[rowbase + 32 + r], t1b[i]);
            }
        }
    } else {
        // ---------- eval: 32 rows, bf16x3, depth-1 prefetch (reg budget)
        const float* lt = ws + WS_LT;
        int* rankacc = (int*)(ws + WS_RANK);
        const int rowbase = (blockIdx.x - 29) * 32;      // eval-local 0..160
        s8b Ah[4], Al[4];
#pragma unroll
        for (int s = 0; s < 4; ++s) {
            const int off = (LROWS_ + rowbase + col)*64 + s*16 + half*8;
            Ah[s] = *(const s8b*)(seq_hi + off);
            Al[s] = *(const s8b*)(seq_lo + off);
        }
        float ltv[16]; int tg[16]; int cnt[16];
#pragma unroll
        for (int i = 0; i < 16; ++i) {
            const int er = rowbase + (i & 3) + 8*(i >> 2) + 4*half;  // 0..191
            ltv[i] = lt[LROWS_ + er] * LOG2E_;           // scaled like acc
            const int b = er/3, j = er - b*3;
            tg[i] = venue[b*L_ + 29 + j];
            cnt[i] = 0;
        }
        s8b Bh[4], Bl[4];
        {
            const unsigned short* ph = vt_hi + (size_t)(tile0 + wave)*2048 + laneoff;
            const unsigned short* pl = vt_lo + (size_t)(tile0 + wave)*2048 + laneoff;
#pragma unroll
            for (int s = 0; s < 4; ++s) {
                Bh[s] = *(const s8b*)(ph + s*16);
                Bl[s] = *(const s8b*)(pl + s*16);
            }
        }
        for (int it = wave; it < CHUNK_; it += 4) {
            int nt = tile0 + it + 4; if (nt >= NTILES_) nt -= NTILES_;
            const unsigned short* ph = vt_hi + (size_t)nt*2048 + laneoff;
            const unsigned short* pl = vt_lo + (size_t)nt*2048 + laneoff;
            f16f acc = {};
#pragma unroll
            for (int s = 0; s < 4; ++s) {
                acc = __builtin_amdgcn_mfma_f32_32x32x16_bf16(Ah[s], Bh[s], acc, 0, 0, 0);
                acc = __builtin_amdgcn_mfma_f32_32x32x16_bf16(Al[s], Bh[s], acc, 0, 0, 0);
                acc = __builtin_amdgcn_mfma_f32_32x32x16_bf16(Ah[s], Bl[s], acc, 0, 0, 0);
                Bh[s] = *(const s8b*)(ph + s*16);
                Bl[s] = *(const s8b*)(pl + s*16);
            }
            const int vid0 = (tile0 + it)*32 + col;
#pragma unroll
            for (int i = 0; i < 16; ++i) {
                const float l = acc[i];
                const bool g = (vid0 != tg[i]) &&
                    (l > ltv[i] || (l == ltv[i] && vid0 < tg[i]));
                cnt[i] += g ? 1 : 0;
            }
        }
#pragma unroll
        for (int i = 0; i < 16; ++i) {
            int v = cnt[i];
#pragma unroll
            for (int m = 1; m <= 16; m <<= 1) v += __shfl_xor(v, m, 64);
            cnt[i] = v;
        }
        if (col == 0) {
#pragma unroll
            for (int i = 0; i < 16; ++i) {
                const int er = rowbase + (i & 3) + 8*(i >> 2) + 4*half;
                atomicAdd(&rankacc[er], cnt[i]);
            }
        }
    }
}

// ---------------- kernel 5: finalize loss + counts ---------------------------
__global__ __launch_bounds__(256)
void fin_kernel(float* __restrict__ ws, float* __restrict__ out)
{
    const float* t1acc = ws + WS_T1;
    const float* lt = ws + WS_LT;
    const int* rankacc = (const int*)(ws + WS_RANK);
    __shared__ float red[256];
    __shared__ int cc[4];
    const int tid = threadIdx.x;
    if (tid < 4) cc[tid] = 0;
    float ls = 0.f;
    for (int r = tid; r < LROWS_; r += 256)
        ls += __expf(lt[r]) / t1acc[r];          // p_t per loss row
    red[tid] = ls;
    __syncthreads();
    for (int s = 128; s > 0; s >>= 1) {
        if (tid < s) red[tid] += red[tid + s];
        __syncthreads();
    }
    if (tid < EROWS_) {
        const int rank = rankacc[tid];
        if (rank < 1)  atomicAdd(&cc[0], 1);
        if (rank < 5)  atomicAdd(&cc[1], 1);
        if (rank < 10) atomicAdd(&cc[2], 1);
        if (rank < 20) atomicAdd(&cc[3], 1);
    }
    __syncthreads();
    if (tid == 0) {
        // loss = mean(log(sum_v e^{p_v})) - mean(p_t); sum_v e^{p_v} ~= NV+1
        out[0] = logf((float)NV_ + 1.0f) - red[0] / (float)LROWS_;
        out[1] = (float)cc[0];
        out[2] = (float)cc[1];
        out[3] = (float)cc[2];
        out[4] = (float)cc[3];
        out[5] = (float)EROWS_;
    }
}

extern "C" void kernel_launch(void* const* d_in, const int* in_sizes, int n_in,
                              void* d_out, int out_size, void* d_ws, size_t ws_size,
                              hipStream_t stream)
{
    const int*   user  = (const int*)d_in[0];
    const int*   venue = (const int*)d_in[1];
    const float* timef = (const float*)d_in[2];
    const float* vt    = (const float*)d_in[3];
    const float* ut    = (const float*)d_in[4];
    const float* w1    = (const float*)d_in[5];
    const float* b1    = (const float*)d_in[6];
    const float* w2    = (const float*)d_in[7];
    const float* b2    = (const float*)d_in[8];
    const float* Wih   = (const float*)d_in[9];
    const float* Whh   = (const float*)d_in[10];
    const float* bih   = (const float*)d_in[11];
    const float* bhh   = (const float*)d_in[12];
    float* ws  = (float*)d_ws;
    float* out = (float*)d_out;

    vtcvt_kernel<<<6250, 256, 0, stream>>>(vt, ws);
    embed_xih_kernel<<<512, 256, 0, stream>>>(venue, timef, vt, w1, b1, w2, b2,
                                              Wih, bih, bhh, ws);
    rnn_kernel<<<64, 64, 0, stream>>>(user, ut, Whh, ws);
    lt_kernel<<<512, 256, 0, stream>>>(venue, vt, ws);
    gemm_kernel<<<dim3(35, NCHUNK_), 256, 0, stream>>>(venue, ws);
    fin_kernel<<<1, 256, 0, stream>>>(ws, out);
}

// Round 4
// 244.996 us; speedup vs baseline: 13.5630x; 13.5630x over previous
//
#include <hip/hip_runtime.h>
#include <math.h>

#define B_    64
#define L_    32
#define D_    64
#define NV_   100000
#define TIN_  8
#define THID_ 128
#define LROWS_ 1856   // 64*29 loss rows
#define EROWS_ 192    // 64*3 eval rows
#define NTILES_ 3125  // 100000/32 exact
#define CHUNK_  125   // tiles per chunk
#define NCHUNK_ 25    // chunks; 25*125 = 3125 exact
#define LOG2E_ 1.44269504088896f

// workspace layout (float-element offsets into ws)
#define WS_TIME_EMB 0        // 2048*64 f32
#define WS_XIH      131072   // 2048*64 f32
#define WS_SEQ      262144   // 2048*64 f32 (unscaled, for lt/fin)
#define WS_LT       393216   // 2048 f32
#define WS_T1       395264   // 1856 f32 (zeroed by embed_xih)
#define WS_RANK     397120   // 192 int  (zeroed by embed_xih; contiguous after T1)
#define WS_SEQH     397312   // 2048*64 ushort (bf16 hi of seq*log2e)
#define WS_SEQL     462848   // 2048*64 ushort (bf16 lo of seq*log2e)
#define WS_VTH      528384   // 100000*64 ushort (bf16 hi of vt)
#define WS_VTL      3728384  // 100000*64 ushort (bf16 lo of vt)
// end: 6928384 floats = 27.7 MB

typedef __attribute__((ext_vector_type(8)))  short s8b;   // 8 bf16 = 4 VGPR
typedef __attribute__((ext_vector_type(16))) float f16f;  // MFMA 32x32 acc

__device__ __forceinline__ unsigned short f2bf(float x) {  // RNE fp32->bf16
    unsigned u = __float_as_uint(x);
    unsigned r = u + 0x7fffu + ((u >> 16) & 1u);
    return (unsigned short)(r >> 16);
}
__device__ __forceinline__ float bf2f(unsigned short h) {
    return __uint_as_float(((unsigned)h) << 16);
}

// ---------------- kernel 0: venue_table fp32 -> bf16 hi/lo split -------------
__global__ __launch_bounds__(256)
void vtcvt_kernel(const float* __restrict__ vt, float* __restrict__ ws)
{
    unsigned short* vh = (unsigned short*)(ws + WS_VTH);
    unsigned short* vl = (unsigned short*)(ws + WS_VTL);
    const int idx = blockIdx.x * 256 + threadIdx.x;   // 0..1599999 (float4 units)
    const float4 x = ((const float4*)vt)[idx];
    ushort4 h, l;
    h.x = f2bf(x.x); l.x = f2bf(x.x - bf2f(h.x));
    h.y = f2bf(x.y); l.y = f2bf(x.y - bf2f(h.y));
    h.z = f2bf(x.z); l.z = f2bf(x.z - bf2f(h.z));
    h.w = f2bf(x.w); l.w = f2bf(x.w - bf2f(h.w));
    *(ushort4*)(vh + idx * 4) = h;
    *(ushort4*)(vl + idx * 4) = l;
}

// ---------------- kernel 1: fused time-MLP + gather + xih + accum zeroing ----
// 512 blocks x 256 threads; one row per wave.
__global__ __launch_bounds__(256)
void embed_xih_kernel(const int* __restrict__ venue, const float* __restrict__ timef,
                      const float* __restrict__ vt, const float* __restrict__ w1,
                      const float* __restrict__ b1, const float* __restrict__ w2,
                      const float* __restrict__ b2, const float* __restrict__ Wih,
                      const float* __restrict__ bih, const float* __restrict__ bhh,
                      float* __restrict__ ws)
{
    float* time_emb = ws + WS_TIME_EMB;
    float* xih = ws + WS_XIH;
    const int wave = threadIdx.x >> 6, d = threadIdx.x & 63;
    const int row = blockIdx.x * 4 + wave;          // 0..2047
    const int g = blockIdx.x * 256 + threadIdx.x;
    if (g < LROWS_ + EROWS_) ws[WS_T1 + g] = 0.f;   // zero T1 (1856) + rank (192)
    __shared__ float hid[4][THID_];
    __shared__ float xrow[4][D_];
    float t[TIN_];
#pragma unroll
    for (int k = 0; k < TIN_; ++k) t[k] = timef[row*TIN_ + k];
#pragma unroll
    for (int h = d; h < THID_; h += 64) {
        float s = b1[h];
#pragma unroll
        for (int k = 0; k < TIN_; ++k) s = fmaf(t[k], w1[k*THID_ + h], s);
        hid[wave][h] = fmaxf(s, 0.f);
    }
    __syncthreads();
    float v = b2[d];
#pragma unroll 16
    for (int h = 0; h < THID_; ++h) v = fmaf(hid[wave][h], w2[h*D_ + d], v);
    time_emb[row*D_ + d] = v;
    xrow[wave][d] = vt[(size_t)venue[row]*D_ + d] + v;
    __syncthreads();
    float acc = bih[d] + bhh[d];
    const float* wr = Wih + (size_t)d*D_;
#pragma unroll 16
    for (int k = 0; k < D_; ++k) acc = fmaf(xrow[wave][k], wr[k], acc);
    xih[row*D_ + d] = acc;
}

// ---------------- kernel 2: RNN, one wave per batch element ------------------
__device__ __forceinline__ void store_seq(float* __restrict__ ws, int gr, int d, float v)
{
    (ws + WS_SEQ)[gr*D_ + d] = v;                 // unscaled fp32 for lt
    const float sv = v * LOG2E_;                  // scaled: exp(l) = exp2(acc)
    const unsigned short hb = f2bf(sv);
    const unsigned short lb = f2bf(sv - bf2f(hb));
    ((unsigned short*)(ws + WS_SEQH))[gr*D_ + d] = hb;
    ((unsigned short*)(ws + WS_SEQL))[gr*D_ + d] = lb;
}

__global__ __launch_bounds__(64)
void rnn_kernel(const int* __restrict__ user, const float* __restrict__ user_table,
                const float* __restrict__ Whh, float* __restrict__ ws)
{
    const float* time_emb = ws + WS_TIME_EMB;
    const float* xih = ws + WS_XIH;
    const int b = blockIdx.x, d = threadIdx.x;
    __shared__ float h_lds[D_];
    float whh[D_];
#pragma unroll
    for (int k = 0; k < D_; ++k) whh[k] = Whh[d*D_ + k];
    float h = user_table[(size_t)user[b]*D_ + d];
    for (int l = 0; l < 31; ++l) {
        const float te = time_emb[(b*L_ + l)*D_ + d];
        const int gr = (l < 29) ? (b*29 + l) : (LROWS_ + b*3 + (l - 29));
        store_seq(ws, gr, d, h - te);
        h_lds[d] = h;
        __syncthreads();
        float acc = xih[(b*L_ + l)*D_ + d];
#pragma unroll
        for (int k = 0; k < D_; ++k) acc = fmaf(whh[k], h_lds[k], acc);
        __syncthreads();
        h = tanhf(acc);
    }
    store_seq(ws, LROWS_ + b*3 + 2, d, h - time_emb[(b*L_ + 31)*D_ + d]);
}

// ---------------- kernel 3: target logits l_t for all 2048 rows (fp32) -------
__global__ __launch_bounds__(256)
void lt_kernel(const int* __restrict__ venue, const float* __restrict__ vt,
               float* __restrict__ ws)
{
    const float* seq = ws + WS_SEQ;
    float* lt = ws + WS_LT;
    const int wid = threadIdx.x >> 6, lane = threadIdx.x & 63;
    const int row = blockIdx.x*4 + wid;      // 0..2047
    int tgt;
    if (row < LROWS_) {
        const int b = row/29, l = row - b*29;
        tgt = venue[b*L_ + l];
    } else {
        const int r2 = row - LROWS_;
        const int b = r2/3, j = r2 - b*3;
        tgt = venue[b*L_ + 29 + j];
    }
    float v = seq[(size_t)row*D_ + lane] * vt[(size_t)tgt*D_ + lane];
#pragma unroll
    for (int m = 32; m >= 1; m >>= 1) v += __shfl_xor(v, m, 64);
    if (lane == 0) lt[row] = v;
}

// ---------------- kernel 4: fused MFMA GEMM (loss: bf16 + exp2-sum; eval:
// bf16x3 + rank count). grid (35, 25): x<29 loss 64-row blocks, x>=29 eval
// 32-row blocks; y = venue chunk of 125 tiles, 4 waves stride the tiles.
// NOTE: register double-buffer uses STATIC names (Bb0/Bb1) + manual unroll-by-2
// — dynamic indexing of a register array sends it to scratch (round-3 lesson).
__global__ __launch_bounds__(256)
void gemm_kernel(const int* __restrict__ venue, float* __restrict__ ws)
{
    const unsigned short* seq_hi = (const unsigned short*)(ws + WS_SEQH);
    const unsigned short* seq_lo = (const unsigned short*)(ws + WS_SEQL);
    const unsigned short* vt_hi  = (const unsigned short*)(ws + WS_VTH);
    const unsigned short* vt_lo  = (const unsigned short*)(ws + WS_VTL);
    const int lane = threadIdx.x & 63, wave = threadIdx.x >> 6;
    const int col = lane & 31, half = lane >> 5;
    const int tile0 = blockIdx.y * CHUNK_;
    const int laneoff = col*64 + half*8;      // within-tile short offset

    if (blockIdx.x < 29) {
        // ---------- loss: 64 rows, hi-only (pure bf16), depth-2 prefetch -----
        float* t1acc = ws + WS_T1;
        const int rowbase = blockIdx.x * 64;
        s8b Ah[2][4];
#pragma unroll
        for (int t = 0; t < 2; ++t)
#pragma unroll
            for (int s = 0; s < 4; ++s)
                Ah[t][s] = *(const s8b*)(seq_hi + (rowbase + t*32 + col)*64 + s*16 + half*8);
        float t1a[16], t1b[16];
#pragma unroll
        for (int i = 0; i < 16; ++i) { t1a[i] = 0.f; t1b[i] = 0.f; }
        s8b Bb0[4], Bb1[4];
        {
            const unsigned short* p0 = vt_hi + (size_t)(tile0 + wave)*2048 + laneoff;
            const unsigned short* p1 = vt_hi + (size_t)(tile0 + wave + 4)*2048 + laneoff;
#pragma unroll
            for (int s = 0; s < 4; ++s) {
                Bb0[s] = *(const s8b*)(p0 + s*16);
                Bb1[s] = *(const s8b*)(p1 + s*16);
            }
        }
#define LOSS_TILE(BUF, ITV)                                                       \
        {                                                                         \
            int pf = tile0 + (ITV) + 8; if (pf >= NTILES_) pf -= NTILES_;         \
            const unsigned short* pp = vt_hi + (size_t)pf*2048 + laneoff;         \
            f16f acc0 = {}, acc1 = {};                                            \
            _Pragma("unroll")                                                     \
            for (int s = 0; s < 4; ++s) {                                         \
                acc0 = __builtin_amdgcn_mfma_f32_32x32x16_bf16(Ah[0][s], BUF[s], acc0, 0, 0, 0); \
                acc1 = __builtin_amdgcn_mfma_f32_32x32x16_bf16(Ah[1][s], BUF[s], acc1, 0, 0, 0); \
                BUF[s] = *(const s8b*)(pp + s*16);  /* consumed 2 iters later */  \
            }                                                                     \
            _Pragma("unroll")                                                     \
            for (int i = 0; i < 16; ++i) {                                        \
                t1a[i] += __builtin_amdgcn_exp2f(acc0[i]);                        \
                t1b[i] += __builtin_amdgcn_exp2f(acc1[i]);                        \
            }                                                                     \
        }
        int it = wave;
        for (; it + 4 < CHUNK_; it += 8) {
            LOSS_TILE(Bb0, it)
            LOSS_TILE(Bb1, it + 4)
        }
        if (it < CHUNK_) LOSS_TILE(Bb0, it)
#undef LOSS_TILE
        // reduce over the 32 venue-cols in each half, one atomic per row
#pragma unroll
        for (int i = 0; i < 16; ++i) {
            float a = t1a[i], b = t1b[i];
#pragma unroll
            for (int m = 1; m <= 16; m <<= 1) {
                a += __shfl_xor(a, m, 64);
                b += __shfl_xor(b, m, 64);
            }
            t1a[i] = a; t1b[i] = b;
        }
        if (col == 0) {
#pragma unroll
            for (int i = 0; i < 16; ++i) {
                const int r = (i & 3) + 8*(i >> 2) + 4*half;
                atomicAdd(&t1acc[rowbase + r], t1a[i]);
                atomicAdd(&t1acc[rowbase + 32 + r], t1b[i]);
            }
        }
    } else {
        // ---------- eval: 32 rows, bf16x3, depth-1 prefetch (static indices) --
        const float* lt = ws + WS_LT;
        int* rankacc = (int*)(ws + WS_RANK);
        const int rowbase = (blockIdx.x - 29) * 32;      // eval-local 0..160
        s8b Ah[4], Al[4];
#pragma unroll
        for (int s = 0; s < 4; ++s) {
            const int off = (LROWS_ + rowbase + col)*64 + s*16 + half*8;
            Ah[s] = *(const s8b*)(seq_hi + off);
            Al[s] = *(const s8b*)(seq_lo + off);
        }
        float ltv[16]; int tg[16]; int cnt[16];
#pragma unroll
        for (int i = 0; i < 16; ++i) {
            const int er = rowbase + (i & 3) + 8*(i >> 2) + 4*half;  // 0..191
            ltv[i] = lt[LROWS_ + er] * LOG2E_;           // scaled like acc
            const int b = er/3, j = er - b*3;
            tg[i] = venue[b*L_ + 29 + j];
            cnt[i] = 0;
        }
        s8b Bh[4], Bl[4];
        {
            const unsigned short* ph = vt_hi + (size_t)(tile0 + wave)*2048 + laneoff;
            const unsigned short* pl = vt_lo + (size_t)(tile0 + wave)*2048 + laneoff;
#pragma unroll
            for (int s = 0; s < 4; ++s) {
                Bh[s] = *(const s8b*)(ph + s*16);
                Bl[s] = *(const s8b*)(pl + s*16);
            }
        }
        for (int it = wave; it < CHUNK_; it += 4) {
            int nt = tile0 + it + 4; if (nt >= NTILES_) nt -= NTILES_;
            const unsigned short* ph = vt_hi + (size_t)nt*2048 + laneoff;
            const unsigned short* pl = vt_lo + (size_t)nt*2048 + laneoff;
            f16f acc = {};
#pragma unroll
            for (int s = 0; s < 4; ++s) {
                acc = __builtin_amdgcn_mfma_f32_32x32x16_bf16(Ah[s], Bh[s], acc, 0, 0, 0);
                acc = __builtin_amdgcn_mfma_f32_32x32x16_bf16(Al[s], Bh[s], acc, 0, 0, 0);
                acc = __builtin_amdgcn_mfma_f32_32x32x16_bf16(Ah[s], Bl[s], acc, 0, 0, 0);
                Bh[s] = *(const s8b*)(ph + s*16);
                Bl[s] = *(const s8b*)(pl + s*16);
            }
            const int vid0 = (tile0 + it)*32 + col;
#pragma unroll
            for (int i = 0; i < 16; ++i) {
                const float l = acc[i];
                const bool g = (vid0 != tg[i]) &&
                    (l > ltv[i] || (l == ltv[i] && vid0 < tg[i]));
                cnt[i] += g ? 1 : 0;
            }
        }
#pragma unroll
        for (int i = 0; i < 16; ++i) {
            int v = cnt[i];
#pragma unroll
            for (int m = 1; m <= 16; m <<= 1) v += __shfl_xor(v, m, 64);
            cnt[i] = v;
        }
        if (col == 0) {
#pragma unroll
            for (int i = 0; i < 16; ++i) {
                const int er = rowbase + (i & 3) + 8*(i >> 2) + 4*half;
                atomicAdd(&rankacc[er], cnt[i]);
            }
        }
    }
}

// ---------------- kernel 5: finalize loss + counts ---------------------------
__global__ __launch_bounds__(256)
void fin_kernel(float* __restrict__ ws, float* __restrict__ out)
{
    const float* t1acc = ws + WS_T1;
    const float* lt = ws + WS_LT;
    const int* rankacc = (const int*)(ws + WS_RANK);
    __shared__ float red[256];
    __shared__ int cc[4];
    const int tid = threadIdx.x;
    if (tid < 4) cc[tid] = 0;
    float ls = 0.f;
    for (int r = tid; r < LROWS_; r += 256)
        ls += __expf(lt[r]) / t1acc[r];          // p_t per loss row
    red[tid] = ls;
    __syncthreads();
    for (int s = 128; s > 0; s >>= 1) {
        if (tid < s) red[tid] += red[tid + s];
        __syncthreads();
    }
    if (tid < EROWS_) {
        const int rank = rankacc[tid];
        if (rank < 1)  atomicAdd(&cc[0], 1);
        if (rank < 5)  atomicAdd(&cc[1], 1);
        if (rank < 10) atomicAdd(&cc[2], 1);
        if (rank < 20) atomicAdd(&cc[3], 1);
    }
    __syncthreads();
    if (tid == 0) {
        // loss = mean(log(sum_v e^{p_v})) - mean(p_t); sum_v e^{p_v} ~= NV+1
        out[0] = logf((float)NV_ + 1.0f) - red[0] / (float)LROWS_;
        out[1] = (float)cc[0];
        out[2] = (float)cc[1];
        out[3] = (float)cc[2];
        out[4] = (float)cc[3];
        out[5] = (float)EROWS_;
    }
}

extern "C" void kernel_launch(void* const* d_in, const int* in_sizes, int n_in,
                              void* d_out, int out_size, void* d_ws, size_t ws_size,
                              hipStream_t stream)
{
    const int*   user  = (const int*)d_in[0];
    const int*   venue = (const int*)d_in[1];
    const float* timef = (const float*)d_in[2];
    const float* vt    = (const float*)d_in[3];
    const float* ut    = (const float*)d_in[4];
    const float* w1    = (const float*)d_in[5];
    const float* b1    = (const float*)d_in[6];
    const float* w2    = (const float*)d_in[7];
    const float* b2    = (const float*)d_in[8];
    const float* Wih   = (const float*)d_in[9];
    const float* Whh   = (const float*)d_in[10];
    const float* bih   = (const float*)d_in[11];
    const float* bhh   = (const float*)d_in[12];
    float* ws  = (float*)d_ws;
    float* out = (float*)d_out;

    vtcvt_kernel<<<6250, 256, 0, stream>>>(vt, ws);
    embed_xih_kernel<<<512, 256, 0, stream>>>(venue, timef, vt, w1, b1, w2, b2,
                                              Wih, bih, bhh, ws);
    rnn_kernel<<<64, 64, 0, stream>>>(user, ut, Whh, ws);
    lt_kernel<<<512, 256, 0, stream>>>(venue, vt, ws);
    gemm_kernel<<<dim3(35, NCHUNK_), 256, 0, stream>>>(venue, ws);
    fin_kernel<<<1, 256, 0, stream>>>(ws, out);
}

// Round 5
// 244.041 us; speedup vs baseline: 13.6162x; 1.0039x over previous
//
#include <hip/hip_runtime.h>
#include <math.h>

#define B_    64
#define L_    32
#define D_    64
#define NV_   100000
#define TIN_  8
#define THID_ 128
#define LROWS_ 1856   // 64*29 loss rows
#define EROWS_ 192    // 64*3 eval rows
#define NTILES_ 3125  // 100000/32 exact (valid tiles)
#define PTILES_ 3136  // padded tiles = 49 chunks * 64
#define CHUNK_  64    // tiles per chunk -> exactly 16 tiles per wave
#define NCHUNK_ 49
#define LOG2E_ 1.44269504088896f

// workspace layout (float-element offsets into ws)
#define WS_TIME_EMB 0        // 2048*64 f32
#define WS_XIH      131072   // 2048*64 f32
#define WS_LT       262144   // 2048 f32
#define WS_T1       264192   // 1856 f32 (zeroed by k1)
#define WS_RANK     266048   // 192 int (zeroed by k1; contiguous after T1)
#define WS_SEQH     266240   // 2048*64 ushort (bf16 hi of seq*log2e)
#define WS_SEQL     331776   // 2048*64 ushort (bf16 lo of seq*log2e)
#define WS_VTH      397312   // 3136 tiles * 2048 ushort (bf16 hi; pad uninit=ok)
#define WS_VTL      3608576  // same, bf16 lo
// end: 6819840 f32 = 27.3 MB

typedef __attribute__((ext_vector_type(8)))  short s8b;   // 8 bf16 = 4 VGPR
typedef __attribute__((ext_vector_type(16))) float f16f;  // MFMA 32x32 acc

__device__ __forceinline__ unsigned short f2bf(float x) {  // RNE fp32->bf16
    unsigned u = __float_as_uint(x);
    unsigned r = u + 0x7fffu + ((u >> 16) & 1u);
    return (unsigned short)(r >> 16);
}
__device__ __forceinline__ float bf2f(unsigned short h) {
    return __uint_as_float(((unsigned)h) << 16);
}

// ---------------- kernel 1: vt bf16-split (blocks 0..6249) + time-MLP/gather/
// xih + accumulator zeroing (blocks 6250..6761, one row per wave) -------------
__global__ __launch_bounds__(256)
void k1_kernel(const int* __restrict__ venue, const float* __restrict__ timef,
               const float* __restrict__ vt, const float* __restrict__ w1,
               const float* __restrict__ b1, const float* __restrict__ w2,
               const float* __restrict__ b2, const float* __restrict__ Wih,
               const float* __restrict__ bih, const float* __restrict__ bhh,
               float* __restrict__ ws)
{
    if (blockIdx.x < 6250) {
        unsigned short* vh = (unsigned short*)(ws + WS_VTH);
        unsigned short* vl = (unsigned short*)(ws + WS_VTL);
        const int idx = blockIdx.x * 256 + threadIdx.x;   // float4 units, 1.6e6 total
        const float4 x = ((const float4*)vt)[idx];
        ushort4 h, l;
        h.x = f2bf(x.x); l.x = f2bf(x.x - bf2f(h.x));
        h.y = f2bf(x.y); l.y = f2bf(x.y - bf2f(h.y));
        h.z = f2bf(x.z); l.z = f2bf(x.z - bf2f(h.z));
        h.w = f2bf(x.w); l.w = f2bf(x.w - bf2f(h.w));
        *(ushort4*)(vh + idx * 4) = h;
        *(ushort4*)(vl + idx * 4) = l;
        return;
    }
    const int bx = blockIdx.x - 6250;                // 0..511
    float* time_emb = ws + WS_TIME_EMB;
    float* xih = ws + WS_XIH;
    const int wave = threadIdx.x >> 6, d = threadIdx.x & 63;
    const int row = bx * 4 + wave;                   // 0..2047
    const int g = bx * 256 + threadIdx.x;
    if (g < LROWS_ + EROWS_) ws[WS_T1 + g] = 0.f;    // zero T1 (1856) + rank (192)
    __shared__ float hid[4][THID_];
    __shared__ float xrow[4][D_];
    float t[TIN_];
#pragma unroll
    for (int k = 0; k < TIN_; ++k) t[k] = timef[row*TIN_ + k];
#pragma unroll
    for (int h = d; h < THID_; h += 64) {
        float s = b1[h];
#pragma unroll
        for (int k = 0; k < TIN_; ++k) s = fmaf(t[k], w1[k*THID_ + h], s);
        hid[wave][h] = fmaxf(s, 0.f);
    }
    __syncthreads();
    float v = b2[d];
#pragma unroll 16
    for (int h = 0; h < THID_; ++h) v = fmaf(hid[wave][h], w2[h*D_ + d], v);
    time_emb[row*D_ + d] = v;
    xrow[wave][d] = vt[(size_t)venue[row]*D_ + d] + v;
    __syncthreads();
    float acc = bih[d] + bhh[d];
    const float* wr = Wih + (size_t)d*D_;
#pragma unroll 16
    for (int k = 0; k < D_; ++k) acc = fmaf(xrow[wave][k], wr[k], acc);
    xih[row*D_ + d] = acc;
}

// ---------------- kernel 2: RNN (one wave per batch elem) + fused lt dots ----
__device__ __forceinline__ void store_seq_bf(float* __restrict__ ws, int gr, int d, float v)
{
    const float sv = v * LOG2E_;                  // scaled: exp(l) = exp2(acc)
    const unsigned short hb = f2bf(sv);
    const unsigned short lb = f2bf(sv - bf2f(hb));
    ((unsigned short*)(ws + WS_SEQH))[gr*D_ + d] = hb;
    ((unsigned short*)(ws + WS_SEQL))[gr*D_ + d] = lb;
}

__global__ __launch_bounds__(64)
void rnn_kernel(const int* __restrict__ user, const int* __restrict__ venue,
                const float* __restrict__ user_table, const float* __restrict__ vt,
                const float* __restrict__ Whh, float* __restrict__ ws)
{
    const int b = blockIdx.x, d = threadIdx.x;
    __shared__ float h_lds[D_];
    __shared__ float seq_s[32][65];               // +1 pad: conflict-free column reads
    float whh[D_];
#pragma unroll
    for (int k = 0; k < D_; ++k) whh[k] = Whh[d*D_ + k];
    float te[L_];                                  // static indices (full unroll below)
#pragma unroll
    for (int l = 0; l < L_; ++l) te[l] = (ws + WS_TIME_EMB)[(b*L_ + l)*D_ + d];
    float xi[31];
#pragma unroll
    for (int l = 0; l < 31; ++l) xi[l] = (ws + WS_XIH)[(b*L_ + l)*D_ + d];
    float h = user_table[(size_t)user[b]*D_ + d];
#pragma unroll
    for (int l = 0; l < 31; ++l) {
        const float v = h - te[l];
        seq_s[l][d] = v;
        const int gr = (l < 29) ? (b*29 + l) : (LROWS_ + b*3 + (l - 29));
        store_seq_bf(ws, gr, d, v);
        h_lds[d] = h;
        __syncthreads();
        float acc = xi[l];
#pragma unroll
        for (int k = 0; k < D_; ++k) acc = fmaf(whh[k], h_lds[k], acc);
        __syncthreads();
        h = tanhf(acc);
    }
    {
        const float v = h - te[31];
        seq_s[31][d] = v;
        store_seq_bf(ws, LROWS_ + b*3 + 2, d, v);
    }
    __syncthreads();
    // fused target-logit dots: thread d<32 handles seq row d of this batch elem
    if (d < 32) {
        const int tgt = venue[b*L_ + d];
        const float* vr = vt + (size_t)tgt*D_;
        float s = 0.f;
#pragma unroll
        for (int k = 0; k < D_; ++k) s = fmaf(seq_s[d][k], vr[k], s);
        const int ltrow = (d < 29) ? (b*29 + d) : (LROWS_ + b*3 + (d - 29));
        (ws + WS_LT)[ltrow] = s;
    }
}

// ---------------- kernel 3: fused MFMA GEMM --------------------------------
// grid (35, 49): x<29 loss 64-row blocks (bf16 hi-only + exp2-sum); x>=29 eval
// 32-row blocks (bf16x3 + rank count). y = 64-tile chunk; each wave: exactly
// 16 tiles, fully unrolled pair loop, acc ping-pong (epilogue of tile j-1
// overlaps MFMAs of tile j), depth-2 (loss) / depth-1 (eval) B prefetch with
// STATIC register names (round-3 lesson: dynamic reg indexing -> scratch).
__global__ __launch_bounds__(256, 2)
void gemm_kernel(const int* __restrict__ venue, float* __restrict__ ws)
{
    const unsigned short* seq_hi = (const unsigned short*)(ws + WS_SEQH);
    const unsigned short* seq_lo = (const unsigned short*)(ws + WS_SEQL);
    const unsigned short* vt_hi  = (const unsigned short*)(ws + WS_VTH);
    const unsigned short* vt_lo  = (const unsigned short*)(ws + WS_VTL);
    const int lane = threadIdx.x & 63, wave = threadIdx.x >> 6;
    const int col = lane & 31, half = lane >> 5;
    const int tile0 = blockIdx.y * CHUNK_;
    const int t0 = tile0 + wave;              // wave's tile j is t0 + 4*j, j=0..15
    const int laneoff = col*64 + half*8;      // within-tile short offset
    const f16f FZERO = {};

    if (blockIdx.x < 29) {
        // ---------------- loss: 64 rows, hi-only bf16 ------------------------
        float* t1acc = ws + WS_T1;
        const int rowbase = blockIdx.x * 64;
        s8b Ah0[4], Ah1[4];
#pragma unroll
        for (int s = 0; s < 4; ++s) {
            Ah0[s] = *(const s8b*)(seq_hi + (rowbase + col)*64 + s*16 + half*8);
            Ah1[s] = *(const s8b*)(seq_hi + (rowbase + 32 + col)*64 + s*16 + half*8);
        }
        float t1a[16], t1b[16];
#pragma unroll
        for (int i = 0; i < 16; ++i) { t1a[i] = 0.f; t1b[i] = 0.f; }
        const unsigned short* tb = vt_hi + laneoff;
        s8b Bb0[4], Bb1[4];
#pragma unroll
        for (int s = 0; s < 4; ++s) {
            Bb0[s] = *(const s8b*)(tb + (size_t)t0*2048 + s*16);
            Bb1[s] = *(const s8b*)(tb + (size_t)(t0 + 4)*2048 + s*16);
        }
        f16f aE0, aE1, aO0, aO1;

#define L_MFMA(A0, A1, BUF, J)                                                    \
        {                                                                         \
            A0 = FZERO; A1 = FZERO;                                               \
            _Pragma("unroll")                                                     \
            for (int s = 0; s < 4; ++s) {                                         \
                A0 = __builtin_amdgcn_mfma_f32_32x32x16_bf16(Ah0[s], BUF[s], A0, 0, 0, 0); \
                A1 = __builtin_amdgcn_mfma_f32_32x32x16_bf16(Ah1[s], BUF[s], A1, 0, 0, 0); \
                if ((J) + 2 < 16)                                                 \
                    BUF[s] = *(const s8b*)(tb + (size_t)(t0 + 4*((J)+2))*2048 + s*16); \
            }                                                                     \
        }
#define L_EXP(A0, A1, J)                                                          \
        if (t0 + 4*(J) < NTILES_) {                                               \
            _Pragma("unroll")                                                     \
            for (int i = 0; i < 16; ++i) {                                        \
                t1a[i] += __builtin_amdgcn_exp2f(A0[i]);                          \
                t1b[i] += __builtin_amdgcn_exp2f(A1[i]);                          \
            }                                                                     \
        }
#pragma unroll
        for (int p = 0; p < 8; ++p) {
            L_MFMA(aE0, aE1, Bb0, 2*p)
            if (p > 0) L_EXP(aO0, aO1, 2*p - 1)
            L_MFMA(aO0, aO1, Bb1, 2*p + 1)
            L_EXP(aE0, aE1, 2*p)
        }
        L_EXP(aO0, aO1, 15)
#undef L_MFMA
#undef L_EXP
        // reduce over 32 venue-cols per half, one atomic per row
#pragma unroll
        for (int i = 0; i < 16; ++i) {
            float a = t1a[i], b = t1b[i];
#pragma unroll
            for (int m = 1; m <= 16; m <<= 1) {
                a += __shfl_xor(a, m, 64);
                b += __shfl_xor(b, m, 64);
            }
            t1a[i] = a; t1b[i] = b;
        }
        if (col == 0) {
#pragma unroll
            for (int i = 0; i < 16; ++i) {
                const int r = (i & 3) + 8*(i >> 2) + 4*half;
                atomicAdd(&t1acc[rowbase + r], t1a[i]);
                atomicAdd(&t1acc[rowbase + 32 + r], t1b[i]);
            }
        }
    } else {
        // ---------------- eval: 32 rows, bf16x3, rank counting ---------------
        const float* lt = ws + WS_LT;
        int* rankacc = (int*)(ws + WS_RANK);
        const int rowbase = (blockIdx.x - 29) * 32;      // eval-local 0..160
        s8b Ah[4], Al[4];
#pragma unroll
        for (int s = 0; s < 4; ++s) {
            const int off = (LROWS_ + rowbase + col)*64 + s*16 + half*8;
            Ah[s] = *(const s8b*)(seq_hi + off);
            Al[s] = *(const s8b*)(seq_lo + off);
        }
        float ltv[16]; int tg[16]; int cnt[16];
#pragma unroll
        for (int i = 0; i < 16; ++i) {
            const int er = rowbase + (i & 3) + 8*(i >> 2) + 4*half;  // 0..191
            ltv[i] = lt[LROWS_ + er] * LOG2E_;           // scaled like acc
            const int b = er/3, j = er - b*3;
            tg[i] = venue[b*L_ + 29 + j];
            cnt[i] = 0;
        }
        const unsigned short* tbh = vt_hi + laneoff;
        const unsigned short* tbl = vt_lo + laneoff;
        s8b Bh[4], Bl[4];
#pragma unroll
        for (int s = 0; s < 4; ++s) {
            Bh[s] = *(const s8b*)(tbh + (size_t)t0*2048 + s*16);
            Bl[s] = *(const s8b*)(tbl + (size_t)t0*2048 + s*16);
        }
        f16f aE, aO;

#define E_MFMA(ACC, J)                                                            \
        {                                                                         \
            ACC = FZERO;                                                          \
            _Pragma("unroll")                                                     \
            for (int s = 0; s < 4; ++s) {                                         \
                ACC = __builtin_amdgcn_mfma_f32_32x32x16_bf16(Ah[s], Bh[s], ACC, 0, 0, 0); \
                ACC = __builtin_amdgcn_mfma_f32_32x32x16_bf16(Al[s], Bh[s], ACC, 0, 0, 0); \
                ACC = __builtin_amdgcn_mfma_f32_32x32x16_bf16(Ah[s], Bl[s], ACC, 0, 0, 0); \
                if ((J) + 1 < 16) {                                               \
                    Bh[s] = *(const s8b*)(tbh + (size_t)(t0 + 4*((J)+1))*2048 + s*16); \
                    Bl[s] = *(const s8b*)(tbl + (size_t)(t0 + 4*((J)+1))*2048 + s*16); \
                }                                                                 \
            }                                                                     \
        }
#define E_CMP(ACC, J)                                                             \
        if (t0 + 4*(J) < NTILES_) {                                               \
            const int vj = (t0 + 4*(J))*32 + col;                                 \
            _Pragma("unroll")                                                     \
            for (int i = 0; i < 16; ++i) {                                        \
                const float l = ACC[i];                                           \
                const bool g = (vj != tg[i]) &&                                   \
                    (l > ltv[i] || (l == ltv[i] && vj < tg[i]));                  \
                cnt[i] += g ? 1 : 0;                                              \
            }                                                                     \
        }
#pragma unroll
        for (int p = 0; p < 8; ++p) {
            E_MFMA(aE, 2*p)
            if (p > 0) E_CMP(aO, 2*p - 1)
            E_MFMA(aO, 2*p + 1)
            E_CMP(aE, 2*p)
        }
        E_CMP(aO, 15)
#undef E_MFMA
#undef E_CMP
#pragma unroll
        for (int i = 0; i < 16; ++i) {
            int v = cnt[i];
#pragma unroll
            for (int m = 1; m <= 16; m <<= 1) v += __shfl_xor(v, m, 64);
            cnt[i] = v;
        }
        if (col == 0) {
#pragma unroll
            for (int i = 0; i < 16; ++i) {
                const int er = rowbase + (i & 3) + 8*(i >> 2) + 4*half;
                atomicAdd(&rankacc[er], cnt[i]);
            }
        }
    }
}

// ---------------- kernel 4: finalize loss + counts ---------------------------
__global__ __launch_bounds__(256)
void fin_kernel(float* __restrict__ ws, float* __restrict__ out)
{
    const float* t1acc = ws + WS_T1;
    const float* lt = ws + WS_LT;
    const int* rankacc = (const int*)(ws + WS_RANK);
    __shared__ float red[256];
    __shared__ int cc[4];
    const int tid = threadIdx.x;
    if (tid < 4) cc[tid] = 0;
    float ls = 0.f;
    for (int r = tid; r < LROWS_; r += 256)
        ls += __expf(lt[r]) / t1acc[r];          // p_t per loss row
    red[tid] = ls;
    __syncthreads();
    for (int s = 128; s > 0; s >>= 1) {
        if (tid < s) red[tid] += red[tid + s];
        __syncthreads();
    }
    if (tid < EROWS_) {
        const int rank = rankacc[tid];
        if (rank < 1)  atomicAdd(&cc[0], 1);
        if (rank < 5)  atomicAdd(&cc[1], 1);
        if (rank < 10) atomicAdd(&cc[2], 1);
        if (rank < 20) atomicAdd(&cc[3], 1);
    }
    __syncthreads();
    if (tid == 0) {
        // loss = mean(log(sum_v e^{p_v})) - mean(p_t); sum_v e^{p_v} ~= NV+1
        out[0] = logf((float)NV_ + 1.0f) - red[0] / (float)LROWS_;
        out[1] = (float)cc[0];
        out[2] = (float)cc[1];
        out[3] = (float)cc[2];
        out[4] = (float)cc[3];
        out[5] = (float)EROWS_;
    }
}

extern "C" void kernel_launch(void* const* d_in, const int* in_sizes, int n_in,
                              void* d_out, int out_size, void* d_ws, size_t ws_size,
                              hipStream_t stream)
{
    const int*   user  = (const int*)d_in[0];
    const int*   venue = (const int*)d_in[1];
    const float* timef = (const float*)d_in[2];
    const float* vt    = (const float*)d_in[3];
    const float* ut    = (const float*)d_in[4];
    const float* w1    = (const float*)d_in[5];
    const float* b1    = (const float*)d_in[6];
    const float* w2    = (const float*)d_in[7];
    const float* b2    = (const float*)d_in[8];
    const float* Wih   = (const float*)d_in[9];
    const float* Whh   = (const float*)d_in[10];
    const float* bih   = (const float*)d_in[11];
    const float* bhh   = (const float*)d_in[12];
    float* ws  = (float*)d_ws;
    float* out = (float*)d_out;

    k1_kernel<<<6762, 256, 0, stream>>>(venue, timef, vt, w1, b1, w2, b2,
                                        Wih, bih, bhh, ws);
    rnn_kernel<<<64, 64, 0, stream>>>(user, venue, ut, vt, Whh, ws);
    gemm_kernel<<<dim3(35, NCHUNK_), 256, 0, stream>>>(venue, ws);
    fin_kernel<<<1, 256, 0, stream>>>(ws, out);
}